// Round 8
// baseline (233.077 us; speedup 1.0000x reference)
//
#include <hip/hip_runtime.h>

// IGANN: per-feature 2-layer MLPs (1->16->16->1), summed over 256 features + linear term.
// R8: everything the inner loop touches lives in LDS as f16 (x, W1, b1, W2) or f32 (b2, W3),
//     staged coalesced once per block. Inner loop: ds_read + VALU + MFMA, zero global loads.
//     R6/R7 were phase-latency bound (VALUBusy ~30%): per-feature global weight loads (R6)
//     or serial register preload + tiny blocks (R7). LDS cut to 24 KB -> 6 blocks/CU, so
//     resident blocks' stage/compute phases overlap. FCHUNK=16, grid 2048 (R6 shape:
//     x fetched once, 64-B row slices). Strides 20 f16 = 40 B: 8-B aligned for b64 reads,
//     row*10 mod 32 distinct for r=0..15 -> conflict-free (2-way over 64 lanes = free).

typedef float    f32x4 __attribute__((ext_vector_type(4)));
typedef _Float16 f16x4 __attribute__((ext_vector_type(4)));
typedef __fp16   pk16x2 __attribute__((ext_vector_type(2)));

__device__ __forceinline__ f16x4 cvt4(f32x4 v) {
    pk16x2 lo = __builtin_amdgcn_cvt_pkrtz(v[0], v[1]);
    pk16x2 hi = __builtin_amdgcn_cvt_pkrtz(v[2], v[3]);
    union { unsigned u[2]; f16x4 h; } un;
    un.u[0] = __builtin_bit_cast(unsigned, lo);
    un.u[1] = __builtin_bit_cast(unsigned, hi);
    return un.h;
}

__device__ __forceinline__ f16x4 relu_h(f16x4 v) {
    f16x4 z = {};
    return __builtin_elementwise_max(v, z);
}

__device__ __forceinline__ f32x4 relu_f(f32x4 v) {
    f32x4 z = {0.f, 0.f, 0.f, 0.f};
    return __builtin_elementwise_max(v, z);
}

#define FCHUNK 16   // features per block (16 groups of 16 = 256)
#define XR     20   // x LDS row stride in f16 (40 B: b64-aligned, conflict-free banks)
#define W2R    20   // W2 LDS row stride in f16

__global__ __launch_bounds__(256, 6) void igann_kernel(
    const float* __restrict__ x,  const float* __restrict__ la,
    const float* __restrict__ bb, const float* __restrict__ W1,
    const float* __restrict__ b1, const float* __restrict__ W2,
    const float* __restrict__ b2, const float* __restrict__ W3,
    const float* __restrict__ b3, float* __restrict__ out)
{
    const int tid = threadIdx.x;
    const int l   = tid & 63;     // lane
    const int w   = tid >> 6;     // wave in block (0..3)
    const int r   = l & 15;       // MFMA row m (A) / col n (D)
    const int g   = l >> 4;       // k-group
    const int g4  = g * 4;

    const int rb = blockIdx.x >> 4;    // row block (0..127), 256 rows each
    const int fg = blockIdx.x & 15;    // feature group (0..15)
    const int f0 = fg * FCHUNK;
    const int rowbase = rb * 256;

    __shared__ _Float16 xs [256 * XR];           // 10240 B: x slice [row][col16+pad]
    __shared__ _Float16 w2s[FCHUNK * 16 * W2R];  // 10240 B: [f][n][k16+pad]
    __shared__ _Float16 w1s[FCHUNK * 16];        //   512 B: [f][k]
    __shared__ _Float16 b1s[FCHUNK * 16];        //   512 B
    __shared__ float    b2s[FCHUNK * 16];        //  1024 B: [f][n]
    __shared__ float    w3s[FCHUNK * 16];        //  1024 B
    __shared__ float    red[256];                //  1024 B   -> total 24 KB

    // ---- stage x slice (coalesced: 4 lanes cover one 64-B row-slice) ----
    {
        const int rr = tid >> 2;          // 0..63
        const int c4 = (tid & 3) * 4;     // 0,4,8,12
        #pragma unroll
        for (int it = 0; it < 4; ++it) {
            const int row = it * 64 + rr;
            f32x4 v = *(const f32x4*)(x + (size_t)(rowbase + row) * 256 + f0 + c4);
            *(f16x4*)(xs + row * XR + c4) = cvt4(v);
        }
    }
    // ---- stage W2 chunk (4096 floats; thread tid owns row (f,n)=(tid>>4,tid&15)) ----
    {
        const int f = tid >> 4, n = tid & 15;
        const float* src = W2 + ((size_t)(f0 + f) * 16 + n) * 16;
        _Float16* dst = w2s + (f * 16 + n) * W2R;
        #pragma unroll
        for (int q = 0; q < 4; ++q) {
            f32x4 v = *(const f32x4*)(src + q * 4);
            *(f16x4*)(dst + q * 4) = cvt4(v);
        }
    }
    // ---- stage W1/b1 (f16), b2/W3 (f32): one element per thread ----
    w1s[tid] = (_Float16)W1[f0 * 16 + tid];
    b1s[tid] = (_Float16)b1[f0 * 16 + tid];
    b2s[tid] = b2[f0 * 16 + tid];
    w3s[tid] = W3[f0 * 16 + tid];
    __syncthreads();

    const _Float16* xw = xs + (w * 64 + r) * XR;

    f32x4 acc[4];     // [tile][j]: D row g4+j (batch row within tile), col r (channel)
    #pragma unroll
    for (int t = 0; t < 4; ++t) acc[t] = (f32x4){0.f, 0.f, 0.f, 0.f};

    #pragma unroll
    for (int fi = 0; fi < FCHUNK; fi += 4) {
        f16x4 xv[4];
        #pragma unroll
        for (int t = 0; t < 4; ++t)
            xv[t] = *(const f16x4*)(xw + t * 16 * XR + fi);

        #pragma unroll
        for (int u = 0; u < 4; ++u) {
            const int f = fi + u;
            f16x4 w1h   = *(const f16x4*)(w1s + f * 16 + g4);
            f16x4 b1h   = *(const f16x4*)(b1s + f * 16 + g4);
            f16x4 bfrag = *(const f16x4*)(w2s + (f * 16 + r) * W2R + g4);
            const float b2k = b2s[f * 16 + r];
            const float w3k = w3s[f * 16 + r];
            const f32x4 cinit = {b2k, b2k, b2k, b2k};   // b2 folded into MFMA C
            const f32x4 w3k4  = {w3k, w3k, w3k, w3k};

            #pragma unroll
            for (int t = 0; t < 4; ++t) {
                const _Float16 s = xv[t][u];
                f16x4 xb = {s, s, s, s};
                f16x4 h = relu_h(xb * w1h + b1h);       // v_pk_fma_f16 + v_pk_max_f16
                f32x4 d = __builtin_amdgcn_mfma_f32_16x16x16f16(h, bfrag, cinit, 0, 0, 0);
                acc[t] += relu_f(d) * w3k4;
            }
        }
    }

    // reduce over the 16 output channels (lane bits 0..3); r==0 lanes hold row sums
    #pragma unroll
    for (int t = 0; t < 4; ++t)
        #pragma unroll
        for (int j = 0; j < 4; ++j) {
            float v = acc[t][j];
            v += __shfl_xor(v, 1, 64);
            v += __shfl_xor(v, 2, 64);
            v += __shfl_xor(v, 4, 64);
            v += __shfl_xor(v, 8, 64);
            if (r == 0) red[w * 64 + t * 16 + g4 + j] = v;
        }
    __syncthreads();

    // ---- epilogue: thread tid owns local row tid ----
    float lin = 0.f, b3s = 0.f;
    const _Float16* xrow = xs + tid * XR;
    #pragma unroll
    for (int c = 0; c < FCHUNK; ++c) {
        lin = fmaf((float)xrow[c], la[f0 + c], lin);   // la uniform -> s_loads
        b3s += b3[f0 + c];
    }
    const float v = red[tid] + lin + b3s + (fg == 0 ? bb[0] : 0.f);
    atomicAdd(out + rowbase + tid, v);
}

extern "C" void kernel_launch(void* const* d_in, const int* in_sizes, int n_in,
                              void* d_out, int out_size, void* d_ws, size_t ws_size,
                              hipStream_t stream) {
    const float* x  = (const float*)d_in[0];
    const float* la = (const float*)d_in[1];
    const float* bb = (const float*)d_in[2];
    const float* W1 = (const float*)d_in[3];
    const float* b1 = (const float*)d_in[4];
    const float* W2 = (const float*)d_in[5];
    const float* b2 = (const float*)d_in[6];
    const float* W3 = (const float*)d_in[7];
    const float* b3 = (const float*)d_in[8];
    float* out = (float*)d_out;

    (void)hipMemsetAsync(out, 0, (size_t)out_size * sizeof(float), stream);

    dim3 grid(2048), block(256);
    hipLaunchKernelGGL(igann_kernel, grid, block, 0, stream,
                       x, la, bb, W1, b1, W2, b2, W3, b3, out);
}

// Round 9
// 108.854 us; speedup vs baseline: 2.1412x; 2.1412x over previous
//
#include <hip/hip_runtime.h>

// IGANN: per-feature 2-layer MLPs (1->16->16->1), summed over 256 features + linear term.
// R9 = R8 structure (x + all weights LDS-resident as f16; inner loop is ds_read+VALU+MFMA
//     with ZERO global loads) minus the things that made R8 spill:
//     (1) plain __launch_bounds__(256) — every min-waves>=4 attempt (R3,R4,R8) made the
//         allocator pick a tiny VGPR tier (32/64/40) and spill 100s of MB to scratch.
//         Occupancy is controlled by LDS instead: 24 KB -> 6 blocks/CU = 24 waves/CU.
//     (2) fi-loop rolled (inner 4x4 u,t unroll kept) to cut transient register pressure.

typedef float    f32x4 __attribute__((ext_vector_type(4)));
typedef _Float16 f16x4 __attribute__((ext_vector_type(4)));
typedef __fp16   pk16x2 __attribute__((ext_vector_type(2)));

__device__ __forceinline__ f16x4 cvt4(f32x4 v) {
    pk16x2 lo = __builtin_amdgcn_cvt_pkrtz(v[0], v[1]);
    pk16x2 hi = __builtin_amdgcn_cvt_pkrtz(v[2], v[3]);
    union { unsigned u[2]; f16x4 h; } un;
    un.u[0] = __builtin_bit_cast(unsigned, lo);
    un.u[1] = __builtin_bit_cast(unsigned, hi);
    return un.h;
}

__device__ __forceinline__ f16x4 relu_h(f16x4 v) {
    f16x4 z = {};
    return __builtin_elementwise_max(v, z);
}

__device__ __forceinline__ f32x4 relu_f(f32x4 v) {
    f32x4 z = {0.f, 0.f, 0.f, 0.f};
    return __builtin_elementwise_max(v, z);
}

#define FCHUNK 16   // features per block (16 groups of 16 = 256)
#define XR     20   // x LDS row stride in f16 (40 B: b64-aligned)
#define W2R    20   // W2 LDS row stride in f16

__global__ __launch_bounds__(256) void igann_kernel(
    const float* __restrict__ x,  const float* __restrict__ la,
    const float* __restrict__ bb, const float* __restrict__ W1,
    const float* __restrict__ b1, const float* __restrict__ W2,
    const float* __restrict__ b2, const float* __restrict__ W3,
    const float* __restrict__ b3, float* __restrict__ out)
{
    const int tid = threadIdx.x;
    const int l   = tid & 63;     // lane
    const int w   = tid >> 6;     // wave in block (0..3)
    const int r   = l & 15;       // MFMA row m (A) / col n (D)
    const int g   = l >> 4;       // k-group
    const int g4  = g * 4;

    const int rb = blockIdx.x >> 4;    // row block (0..127), 256 rows each
    const int fg = blockIdx.x & 15;    // feature group (0..15)
    const int f0 = fg * FCHUNK;
    const int rowbase = rb * 256;

    __shared__ _Float16 xs [256 * XR];           // 10240 B: x slice [row][col16+pad]
    __shared__ _Float16 w2s[FCHUNK * 16 * W2R];  // 10240 B: [f][n][k16+pad]
    __shared__ _Float16 w1s[FCHUNK * 16];        //   512 B: [f][k]
    __shared__ _Float16 b1s[FCHUNK * 16];        //   512 B
    __shared__ float    b2s[FCHUNK * 16];        //  1024 B: [f][n]
    __shared__ float    w3s[FCHUNK * 16];        //  1024 B
    __shared__ float    red[256];                //  1024 B   -> total 24 KB

    // ---- stage x slice (coalesced: 4 lanes cover one 64-B row-slice) ----
    {
        const int rr = tid >> 2;          // 0..63
        const int c4 = (tid & 3) * 4;     // 0,4,8,12
        #pragma unroll
        for (int it = 0; it < 4; ++it) {
            const int row = it * 64 + rr;
            f32x4 v = *(const f32x4*)(x + (size_t)(rowbase + row) * 256 + f0 + c4);
            *(f16x4*)(xs + row * XR + c4) = cvt4(v);
        }
    }
    // ---- stage W2 chunk (4096 floats; thread tid owns row (f,n)=(tid>>4,tid&15)) ----
    {
        const int f = tid >> 4, n = tid & 15;
        const float* src = W2 + ((size_t)(f0 + f) * 16 + n) * 16;
        _Float16* dst = w2s + (f * 16 + n) * W2R;
        #pragma unroll
        for (int q = 0; q < 4; ++q) {
            f32x4 v = *(const f32x4*)(src + q * 4);
            *(f16x4*)(dst + q * 4) = cvt4(v);
        }
    }
    // ---- stage W1/b1 (f16), b2/W3 (f32): one element per thread ----
    w1s[tid] = (_Float16)W1[f0 * 16 + tid];
    b1s[tid] = (_Float16)b1[f0 * 16 + tid];
    b2s[tid] = b2[f0 * 16 + tid];
    w3s[tid] = W3[f0 * 16 + tid];
    __syncthreads();

    const _Float16* xw = xs + (w * 64 + r) * XR;

    f32x4 acc[4];     // [tile][j]: D row g4+j (batch row within tile), col r (channel)
    #pragma unroll
    for (int t = 0; t < 4; ++t) acc[t] = (f32x4){0.f, 0.f, 0.f, 0.f};

    for (int fi = 0; fi < FCHUNK; fi += 4) {   // rolled: keeps register pressure down
        f16x4 xv[4];
        #pragma unroll
        for (int t = 0; t < 4; ++t)
            xv[t] = *(const f16x4*)(xw + t * 16 * XR + fi);

        #pragma unroll
        for (int u = 0; u < 4; ++u) {
            const int f = fi + u;
            f16x4 w1h   = *(const f16x4*)(w1s + f * 16 + g4);
            f16x4 b1h   = *(const f16x4*)(b1s + f * 16 + g4);
            f16x4 bfrag = *(const f16x4*)(w2s + (f * 16 + r) * W2R + g4);
            const float b2k = b2s[f * 16 + r];
            const float w3k = w3s[f * 16 + r];
            const f32x4 cinit = {b2k, b2k, b2k, b2k};   // b2 folded into MFMA C
            const f32x4 w3k4  = {w3k, w3k, w3k, w3k};

            #pragma unroll
            for (int t = 0; t < 4; ++t) {
                const _Float16 s = xv[t][u];
                f16x4 xb = {s, s, s, s};
                f16x4 h = relu_h(xb * w1h + b1h);       // v_pk_fma_f16 + v_pk_max_f16
                f32x4 d = __builtin_amdgcn_mfma_f32_16x16x16f16(h, bfrag, cinit, 0, 0, 0);
                acc[t] += relu_f(d) * w3k4;
            }
        }
    }

    // reduce over the 16 output channels (lane bits 0..3); r==0 lanes hold row sums
    #pragma unroll
    for (int t = 0; t < 4; ++t)
        #pragma unroll
        for (int j = 0; j < 4; ++j) {
            float v = acc[t][j];
            v += __shfl_xor(v, 1, 64);
            v += __shfl_xor(v, 2, 64);
            v += __shfl_xor(v, 4, 64);
            v += __shfl_xor(v, 8, 64);
            if (r == 0) red[w * 64 + t * 16 + g4 + j] = v;
        }
    __syncthreads();

    // ---- epilogue: thread tid owns local row tid ----
    float lin = 0.f, b3s = 0.f;
    const _Float16* xrow = xs + tid * XR;
    #pragma unroll
    for (int c = 0; c < FCHUNK; ++c) {
        lin = fmaf((float)xrow[c], la[f0 + c], lin);   // la uniform -> s_loads
        b3s += b3[f0 + c];
    }
    const float v = red[tid] + lin + b3s + (fg == 0 ? bb[0] : 0.f);
    atomicAdd(out + rowbase + tid, v);
}

extern "C" void kernel_launch(void* const* d_in, const int* in_sizes, int n_in,
                              void* d_out, int out_size, void* d_ws, size_t ws_size,
                              hipStream_t stream) {
    const float* x  = (const float*)d_in[0];
    const float* la = (const float*)d_in[1];
    const float* bb = (const float*)d_in[2];
    const float* W1 = (const float*)d_in[3];
    const float* b1 = (const float*)d_in[4];
    const float* W2 = (const float*)d_in[5];
    const float* b2 = (const float*)d_in[6];
    const float* W3 = (const float*)d_in[7];
    const float* b3 = (const float*)d_in[8];
    float* out = (float*)d_out;

    (void)hipMemsetAsync(out, 0, (size_t)out_size * sizeof(float), stream);

    dim3 grid(2048), block(256);
    hipLaunchKernelGGL(igann_kernel, grid, block, 0, stream,
                       x, la, bb, W1, b1, W2, b2, W3, b3, out);
}